// Round 3
// baseline (36.337 us; speedup 1.0000x reference)
//
#include <hip/hip_runtime.h>

// SelectDropMAX: x[B,C,H,W] f32, per-channel (B*C) 28x28 map.
// out = x - 0.9*x*mask, mask = (x == channel_max) | (7x2 block at (y0,x0)).
// Memory-bound: 103MB in + 103MB out.
// R1: nontemporal output stores (kept).
// R2: persistent grid-stride waves, 2-deep software pipeline (load ch i+1
//     while reducing/storing ch i) -> double MLP, hide shuffle-chain latency.

constexpr int Wdim = 28;
constexpr int HW = 28 * 28;       // 784
constexpr int NF4 = HW / 4;       // 196 float4 per channel
constexpr float SUPPRESS = 0.9f;

typedef float f4 __attribute__((ext_vector_type(4)));

__global__ __launch_bounds__(256) void selectdropmax_kernel(
    const float* __restrict__ x,
    const int* __restrict__ mask_y,
    const int* __restrict__ mask_x,
    float* __restrict__ out,
    int nch)
{
    const int lane  = threadIdx.x & 63;
    const int wid   = blockIdx.x * (blockDim.x >> 6) + (threadIdx.x >> 6);
    const int nwave = gridDim.x * (blockDim.x >> 6);
    const bool extra = (lane < (NF4 - 192));   // lanes 0..3 take the tail f4

    const f4* __restrict__ xv = reinterpret_cast<const f4*>(x);
    f4* __restrict__ ov       = reinterpret_cast<f4*>(out);

    auto load_ch = [&](int c, f4& v0, f4& v1, f4& v2, f4& v3, int& y0, int& x0) {
        const f4* __restrict__ xp = xv + (size_t)c * NF4;
        v0 = xp[lane];
        v1 = xp[lane + 64];
        v2 = xp[lane + 128];
        if (extra) v3 = xp[lane + 192];
        y0 = mask_y[c];
        x0 = mask_x[c];
    };

    auto proc_store = [&](int c, f4 v0, f4 v1, f4 v2, f4 v3, int y0, int x0) {
        // per-lane max
        float m = fmaxf(fmaxf(v0.x, v0.y), fmaxf(v0.z, v0.w));
        m = fmaxf(m, fmaxf(fmaxf(v1.x, v1.y), fmaxf(v1.z, v1.w)));
        m = fmaxf(m, fmaxf(fmaxf(v2.x, v2.y), fmaxf(v2.z, v2.w)));
        if (extra) m = fmaxf(m, fmaxf(fmaxf(v3.x, v3.y), fmaxf(v3.z, v3.w)));
        // 64-lane butterfly max (exact fp32 max -> bitwise == vs ref)
        #pragma unroll
        for (int off = 32; off > 0; off >>= 1)
            m = fmaxf(m, __shfl_xor(m, off, 64));

        auto proc = [&](f4 v, int f4idx) -> f4 {
            f4 res;
            const int base = f4idx * 4;
            #pragma unroll
            for (int j = 0; j < 4; ++j) {
                const float val = v[j];
                const int idx = base + j;
                const int h = idx / Wdim;        // magic-mul
                const int w = idx - h * Wdim;
                const bool inblk = (h >= y0) & (h < y0 + 7) & (w >= x0) & (w < x0 + 2);
                const bool msk = (val == m) | inblk;
                const float t = SUPPRESS * val;  // match ref rounding: x - (0.9*x)
                res[j] = msk ? (val - t) : val;
            }
            return res;
        };

        f4* __restrict__ op = ov + (size_t)c * NF4;
        f4 r0 = proc(v0, lane);
        f4 r1 = proc(v1, lane + 64);
        f4 r2 = proc(v2, lane + 128);
        __builtin_nontemporal_store(r0, &op[lane]);
        __builtin_nontemporal_store(r1, &op[lane + 64]);
        __builtin_nontemporal_store(r2, &op[lane + 128]);
        if (extra) {
            f4 r3 = proc(v3, lane + 192);
            __builtin_nontemporal_store(r3, &op[lane + 192]);
        }
    };

    // 2-deep software pipeline over grid-stride channels, unrolled by 2
    // (named A/B register sets; all indexing compile-time static).
    f4 a0, a1, a2, a3 = (f4){0,0,0,0};
    f4 b0, b1, b2, b3 = (f4){0,0,0,0};
    int ay, ax, by, bx;

    int ch = wid;
    if (ch >= nch) return;
    load_ch(ch, a0, a1, a2, a3, ay, ax);

    for (;;) {
        const int chB = ch + nwave;
        const bool haveB = chB < nch;
        if (haveB) load_ch(chB, b0, b1, b2, b3, by, bx);
        proc_store(ch, a0, a1, a2, a3, ay, ax);
        if (!haveB) return;

        const int chC = chB + nwave;
        const bool haveC = chC < nch;
        if (haveC) load_ch(chC, a0, a1, a2, a3, ay, ax);
        proc_store(chB, b0, b1, b2, b3, by, bx);
        if (!haveC) return;
        ch = chC;
    }
}

extern "C" void kernel_launch(void* const* d_in, const int* in_sizes, int n_in,
                              void* d_out, int out_size, void* d_ws, size_t ws_size,
                              hipStream_t stream) {
    const float* x      = (const float*)d_in[0];
    const int*   mask_y = (const int*)d_in[1];
    const int*   mask_x = (const int*)d_in[2];
    float*       out    = (float*)d_out;

    const int nch = in_sizes[1];              // B*C = 32768
    // Persistent-ish: 8 blocks/CU x 256 CUs = 2048 blocks, 4 waves each
    // -> 8192 waves, each pipelines nch/8192 = 4 channels.
    int nblocks = 2048;
    const int max_needed = (nch + 3) / 4;     // 4 waves per block
    if (nblocks > max_needed) nblocks = max_needed;

    hipLaunchKernelGGL(selectdropmax_kernel,
                       dim3(nblocks), dim3(256), 0, stream,
                       x, mask_y, mask_x, out, nch);
}

// Round 4
// 36.121 us; speedup vs baseline: 1.0060x; 1.0060x over previous
//
#include <hip/hip_runtime.h>

// SelectDropMAX: x[B,C,H,W] f32, per-channel (B*C) 28x28 map.
// out = x - 0.9*x*mask, mask = (x == channel_max) | (7x2 block at (y0,x0)).
// Memory-bound: 103MB in + 103MB out (irreducible). One 64-lane wave per
// channel, data register-resident (3-4 float4/lane), shuffle max-reduce.
// R1: nontemporal output stores — best measured (35.3us = 93% of the
//     6.29 TB/s copy ceiling). R2's 2-deep pipeline was a null -> HBM-bound.
// R3: revert to R1 (best variant). This is the roofline.

constexpr int Wdim = 28;
constexpr int HW = 28 * 28;       // 784
constexpr int NF4 = HW / 4;       // 196 float4 per channel
constexpr float SUPPRESS = 0.9f;

typedef float f4 __attribute__((ext_vector_type(4)));

__global__ __launch_bounds__(256) void selectdropmax_kernel(
    const float* __restrict__ x,
    const int* __restrict__ mask_y,
    const int* __restrict__ mask_x,
    float* __restrict__ out,
    int nch)
{
    const int gtid = blockIdx.x * blockDim.x + threadIdx.x;
    const int ch   = gtid >> 6;          // one wave per channel
    const int lane = threadIdx.x & 63;
    if (ch >= nch) return;

    const f4* __restrict__ xp = reinterpret_cast<const f4*>(x) + (size_t)ch * NF4;
    f4* __restrict__ op       = reinterpret_cast<f4*>(out) + (size_t)ch * NF4;

    // Load: lane i takes float4 i, i+64, i+128; lanes 0..3 take 192+i.
    const bool extra = (lane < (NF4 - 192));   // lanes 0..3
    f4 v0 = xp[lane];
    f4 v1 = xp[lane + 64];
    f4 v2 = xp[lane + 128];
    f4 v3 = (f4){0.f, 0.f, 0.f, 0.f};
    if (extra) v3 = xp[lane + 192];

    // Per-lane max
    float m = fmaxf(fmaxf(v0.x, v0.y), fmaxf(v0.z, v0.w));
    m = fmaxf(m, fmaxf(fmaxf(v1.x, v1.y), fmaxf(v1.z, v1.w)));
    m = fmaxf(m, fmaxf(fmaxf(v2.x, v2.y), fmaxf(v2.z, v2.w)));
    if (extra) m = fmaxf(m, fmaxf(fmaxf(v3.x, v3.y), fmaxf(v3.z, v3.w)));

    // 64-lane butterfly max reduce (exact: fp32 max of exact values,
    // so x == m matches the reference bitwise regardless of order)
    #pragma unroll
    for (int off = 32; off > 0; off >>= 1)
        m = fmaxf(m, __shfl_xor(m, off, 64));

    const int y0 = mask_y[ch];
    const int x0 = mask_x[ch];

    auto proc = [&](f4 v, int f4idx) -> f4 {
        f4 res;
        const int base = f4idx * 4;
        #pragma unroll
        for (int j = 0; j < 4; ++j) {
            const float val = v[j];
            const int idx = base + j;
            const int h = idx / Wdim;          // magic-mul, Wdim const
            const int w = idx - h * Wdim;
            const bool inblk = (h >= y0) & (h < y0 + 7) & (w >= x0) & (w < x0 + 2);
            const bool msk = (val == m) | inblk;
            // match ref rounding: x - (0.9*x); separate mul then sub
            const float t = SUPPRESS * val;
            res[j] = msk ? (val - t) : val;
        }
        return res;
    };

    f4 r0 = proc(v0, lane);
    f4 r1 = proc(v1, lane + 64);
    f4 r2 = proc(v2, lane + 128);
    __builtin_nontemporal_store(r0, &op[lane]);
    __builtin_nontemporal_store(r1, &op[lane + 64]);
    __builtin_nontemporal_store(r2, &op[lane + 128]);
    if (extra) {
        f4 r3 = proc(v3, lane + 192);
        __builtin_nontemporal_store(r3, &op[lane + 192]);
    }
}

extern "C" void kernel_launch(void* const* d_in, const int* in_sizes, int n_in,
                              void* d_out, int out_size, void* d_ws, size_t ws_size,
                              hipStream_t stream) {
    const float* x      = (const float*)d_in[0];
    const int*   mask_y = (const int*)d_in[1];
    const int*   mask_x = (const int*)d_in[2];
    float*       out    = (float*)d_out;

    const int nch = in_sizes[1];              // B*C = 32768
    const int waves_per_block = 4;            // 256 threads
    const int nblocks = (nch + waves_per_block - 1) / waves_per_block;

    hipLaunchKernelGGL(selectdropmax_kernel,
                       dim3(nblocks), dim3(256), 0, stream,
                       x, mask_y, mask_x, out, nch);
}